// Round 9
// baseline (112.956 us; speedup 1.0000x reference)
//
#include <hip/hip_runtime.h>
#include <hip/hip_bf16.h>
#include <math.h>

#define NN 10000
#define DD 16
#define FF 256
#define TN 16   // nodes per block (4 waves x 4 nodes)

typedef float f32x4 __attribute__((ext_vector_type(4)));
#define DOT4(a, b) ((a)[0]*(b)[0] + (a)[1]*(b)[1] + (a)[2]*(b)[2] + (a)[3]*(b)[3])

// ws layout (floats): [0:256) v_tgt, [256:512) u1, [512:768) u2, [768] c0
// stage-1 partials live in the tail of d_out (read by k_pre2 BEFORE k_fused
// overwrites all of d_out): part[16][3][256] floats.

// ---------------- precomp stage 1: 16 blocks, 16 f's each ----------------
__global__ __launch_bounds__(256) void k_pre1(
    const float* __restrict__ Wp, const float* __restrict__ Wa,
    const float* __restrict__ a_src, const float* __restrict__ a_tgt,
    float* __restrict__ part) {
  const int t = threadIdx.x, b = blockIdx.x;
  float s1 = 0.f, s2 = 0.f, vt = 0.f;
  #pragma unroll
  for (int k = 0; k < 16; ++k) {
    const int f = b * 16 + k;
    const float as = a_src[f];
    s1 += as * Wa[f * 2 * FF + t];        // partial w1[t]
    s2 += as * Wa[f * 2 * FF + FF + t];   // partial w2[t]
    vt += a_tgt[f] * Wp[f * FF + t];      // partial v_tgt[t]
  }
  part[(b * 3 + 0) * FF + t] = s1;
  part[(b * 3 + 1) * FF + t] = s2;
  part[(b * 3 + 2) * FF + t] = vt;
}

// ---------------- precomp stage 2: 8 blocks, 32 output cols each ----------
__global__ __launch_bounds__(256) void k_pre2(
    const float* __restrict__ Wp, const float* __restrict__ ba,
    const float* __restrict__ a_src, const float* __restrict__ part,
    float* __restrict__ pre) {
  __shared__ float w1[FF], w2[FF];
  __shared__ float pu1[8][32], pu2[8][32];
  const int t = threadIdx.x;

  float a0 = 0.f, a1 = 0.f, a2 = 0.f;
  #pragma unroll
  for (int b = 0; b < 16; ++b) {
    a0 += part[(b * 3 + 0) * FF + t];
    a1 += part[(b * 3 + 1) * FF + t];
    a2 += part[(b * 3 + 2) * FF + t];
  }
  w1[t] = a0; w2[t] = a1;
  if (blockIdx.x == 0) {
    pre[t] = a2;                           // v_tgt
    if (t < 64) {
      float cp = 0.f;
      #pragma unroll
      for (int k = 0; k < 4; ++k) cp += ba[t + 64 * k] * a_src[t + 64 * k];
      #pragma unroll
      for (int o = 32; o > 0; o >>= 1) cp += __shfl_xor(cp, o);
      if (t == 0) pre[3 * FF] = cp;        // c0
    }
  }
  __syncthreads();

  const int tc = t & 31;                   // column within slice
  const int gc = t >> 5;                   // g-chunk 0..7
  const int tt = blockIdx.x * 32 + tc;     // global output column
  float u1 = 0.f, u2 = 0.f;
  #pragma unroll 4
  for (int g = gc * 32; g < gc * 32 + 32; ++g) {
    const float wpg = Wp[g * FF + tt];
    u1 += w1[g] * wpg;
    u2 += w2[g] * wpg;
  }
  pu1[gc][tc] = u1; pu2[gc][tc] = u2;
  __syncthreads();
  if (t < 32) {
    float r1 = 0.f, r2 = 0.f;
    #pragma unroll
    for (int k = 0; k < 8; ++k) { r1 += pu1[k][t]; r2 += pu2[k][t]; }
    pre[FF + blockIdx.x * 32 + t] = r1;
    pre[2 * FF + blockIdx.x * 32 + t] = r2;
  }
}

// ---------------- fused attention + aggregation + projection --------------
// R9: wave-per-node (zero barriers in the attn phase; one barrier total).
// Each wave processes 4 nodes fully in registers: phase A reads the 16
// neighbor rows (dot u1), phase B reads the 16 aspect rows (dot u2) —
// the two HBM streams are never read in lockstep (channel-decorrelation
// test). agg rows land in LDS; a single barrier precedes the projection.
__global__ __launch_bounds__(256) void k_fused(
    const float* __restrict__ nodes, const float* __restrict__ neighbors,
    const float* __restrict__ aspects, const float* __restrict__ pre,
    const float* __restrict__ Wp, const float* __restrict__ bias,
    float* __restrict__ out) {
  const int tid = threadIdx.x;
  const int wid = tid >> 6;
  const int lane = tid & 63;
  const int n0 = blockIdx.x * TN;

  __shared__ float ag[TN][FF];   // 16 KB aggregated rows for this block

  const f32x4 u1v = ((const f32x4*)(pre + FF))[lane];
  const f32x4 u2v = ((const f32x4*)(pre + 2 * FF))[lane];
  const f32x4 vtv = ((const f32x4*)(pre))[lane];
  const float c0 = pre[3 * FF];

  // each wave owns 4 consecutive nodes; no cross-wave interaction until proj
  #pragma unroll 1
  for (int j = 0; j < 4; ++j) {
    const int i = wid * 4 + j;             // slot in ag
    const int n = n0 + i;
    const f32x4* __restrict__ nbg = (const f32x4*)(neighbors + (size_t)n * DD * FF);
    const f32x4* __restrict__ asg = (const f32x4*)(aspects + (size_t)n * DD * FF);

    // ---- phase A: neighbor rows (kept in regs for the agg step) ----
    f32x4 nbv[DD];
    #pragma unroll
    for (int r = 0; r < DD; ++r)
      nbv[r] = __builtin_nontemporal_load(&nbg[r * 64 + lane]);

    float p[DD + 1];
    #pragma unroll
    for (int r = 0; r < DD; ++r) p[r] = DOT4(nbv[r], u1v);

    // ---- phase B: aspect rows (consumed immediately) ----
    #pragma unroll
    for (int r = 0; r < DD; ++r) {
      const f32x4 av = __builtin_nontemporal_load(&asg[r * 64 + lane]);
      p[r] += DOT4(av, u2v);
    }
    const f32x4 nv = ((const f32x4*)(nodes + (size_t)n * FF))[lane];
    p[DD] = DOT4(nv, vtv);

    // 17-value interleaved butterfly; every lane ends with all full sums
    #pragma unroll
    for (int o = 32; o > 0; o >>= 1) {
      #pragma unroll
      for (int r = 0; r < DD + 1; ++r) p[r] += __shfl_xor(p[r], o);
    }

    float esum = 0.f;
    float e[DD];
    #pragma unroll
    for (int r = 0; r < DD; ++r) {
      float s = p[r] + p[DD] + c0;
      s = s > 0.f ? s : 0.2f * s;          // leaky_relu(0.2)
      e[r] = __expf(s);
      esum += e[r];
    }
    const float inv = 1.f / (esum + 1e-16f);

    // lane-local weighted sum -> ag row
    f32x4 acc = (f32x4)(0.f);
    #pragma unroll
    for (int r = 0; r < DD; ++r) {
      acc[0] += e[r] * nbv[r][0];
      acc[1] += e[r] * nbv[r][1];
      acc[2] += e[r] * nbv[r][2];
      acc[3] += e[r] * nbv[r][3];
    }
    acc[0] *= inv; acc[1] *= inv; acc[2] *= inv; acc[3] *= inv;
    ((f32x4*)&ag[i][0])[lane] = acc;
  }

  __syncthreads();   // the only barrier: ag complete

  // ---- projection: out = elu(ag @ Wp.T + bias), ag LDS-resident ----
  float acc[TN];
  #pragma unroll
  for (int i = 0; i < TN; ++i) acc[i] = 0.f;

  const f32x4* wrow = (const f32x4*)(Wp + (size_t)tid * FF);
  for (int f4 = 0; f4 < FF / 4; ++f4) {
    const f32x4 w = wrow[f4];
    #pragma unroll
    for (int i = 0; i < TN; ++i) {
      const f32x4 a = ((const f32x4*)&ag[i][0])[f4];  // LDS broadcast
      acc[i] += DOT4(a, w);
    }
  }

  const float b = bias[tid];
  #pragma unroll
  for (int i = 0; i < TN; ++i) {
    float v = acc[i] + b;
    out[(size_t)(n0 + i) * FF + tid] = v > 0.f ? v : expm1f(v);  // elu
  }
}

extern "C" void kernel_launch(void* const* d_in, const int* in_sizes, int n_in,
                              void* d_out, int out_size, void* d_ws, size_t ws_size,
                              hipStream_t stream) {
  const float* nodes     = (const float*)d_in[0];
  const float* neighbors = (const float*)d_in[1];
  const float* aspects   = (const float*)d_in[2];
  const float* Wp        = (const float*)d_in[3];
  const float* Wa        = (const float*)d_in[4];
  const float* ba        = (const float*)d_in[5];
  const float* a_src     = (const float*)d_in[6];
  const float* a_tgt     = (const float*)d_in[7];
  const float* bias      = (const float*)d_in[8];
  float* out = (float*)d_out;
  float* pre = (float*)d_ws;

  // stage-1 partials parked in the tail of d_out (consumed before k_fused writes)
  float* part = out + (size_t)NN * FF - 16 * 3 * FF;

  k_pre1<<<16, 256, 0, stream>>>(Wp, Wa, a_src, a_tgt, part);
  k_pre2<<<8, 256, 0, stream>>>(Wp, ba, a_src, part, pre);
  k_fused<<<NN / TN, 256, 0, stream>>>(nodes, neighbors, aspects, pre, Wp, bias, out);
}

// Round 10
// 107.700 us; speedup vs baseline: 1.0488x; 1.0488x over previous
//
#include <hip/hip_runtime.h>
#include <hip/hip_bf16.h>
#include <math.h>

#define NN 10000
#define DD 16
#define FF 256
#define TN 8    // nodes per block (4 waves x 2 nodes) -> 1250 blocks, tiny tail

typedef float f32x4 __attribute__((ext_vector_type(4)));
#define DOT4(a, b) ((a)[0]*(b)[0] + (a)[1]*(b)[1] + (a)[2]*(b)[2] + (a)[3]*(b)[3])

// ws layout (floats): [0:256) v_tgt, [256:512) u1, [512:768) u2, [768] c0
// stage-1 partials live in the tail of d_out (read by k_pre2 BEFORE k_fused
// overwrites all of d_out): part[16][3][256] floats.

// ---------------- precomp stage 1: 16 blocks, 16 f's each ----------------
__global__ __launch_bounds__(256) void k_pre1(
    const float* __restrict__ Wp, const float* __restrict__ Wa,
    const float* __restrict__ a_src, const float* __restrict__ a_tgt,
    float* __restrict__ part) {
  const int t = threadIdx.x, b = blockIdx.x;
  float s1 = 0.f, s2 = 0.f, vt = 0.f;
  #pragma unroll
  for (int k = 0; k < 16; ++k) {
    const int f = b * 16 + k;
    const float as = a_src[f];
    s1 += as * Wa[f * 2 * FF + t];        // partial w1[t]
    s2 += as * Wa[f * 2 * FF + FF + t];   // partial w2[t]
    vt += a_tgt[f] * Wp[f * FF + t];      // partial v_tgt[t]
  }
  part[(b * 3 + 0) * FF + t] = s1;
  part[(b * 3 + 1) * FF + t] = s2;
  part[(b * 3 + 2) * FF + t] = vt;
}

// ---------------- precomp stage 2: 8 blocks, 32 output cols each ----------
__global__ __launch_bounds__(256) void k_pre2(
    const float* __restrict__ Wp, const float* __restrict__ ba,
    const float* __restrict__ a_src, const float* __restrict__ part,
    float* __restrict__ pre) {
  __shared__ float w1[FF], w2[FF];
  __shared__ float pu1[8][32], pu2[8][32];
  const int t = threadIdx.x;

  float a0 = 0.f, a1 = 0.f, a2 = 0.f;
  #pragma unroll
  for (int b = 0; b < 16; ++b) {
    a0 += part[(b * 3 + 0) * FF + t];
    a1 += part[(b * 3 + 1) * FF + t];
    a2 += part[(b * 3 + 2) * FF + t];
  }
  w1[t] = a0; w2[t] = a1;
  if (blockIdx.x == 0) {
    pre[t] = a2;                           // v_tgt
    if (t < 64) {
      float cp = 0.f;
      #pragma unroll
      for (int k = 0; k < 4; ++k) cp += ba[t + 64 * k] * a_src[t + 64 * k];
      #pragma unroll
      for (int o = 32; o > 0; o >>= 1) cp += __shfl_xor(cp, o);
      if (t == 0) pre[3 * FF] = cp;        // c0
    }
  }
  __syncthreads();

  const int tc = t & 31;                   // column within slice
  const int gc = t >> 5;                   // g-chunk 0..7
  const int tt = blockIdx.x * 32 + tc;     // global output column
  float u1 = 0.f, u2 = 0.f;
  #pragma unroll 4
  for (int g = gc * 32; g < gc * 32 + 32; ++g) {
    const float wpg = Wp[g * FF + tt];
    u1 += w1[g] * wpg;
    u2 += w2[g] * wpg;
  }
  pu1[gc][tc] = u1; pu2[gc][tc] = u2;
  __syncthreads();
  if (t < 32) {
    float r1 = 0.f, r2 = 0.f;
    #pragma unroll
    for (int k = 0; k < 8; ++k) { r1 += pu1[k][t]; r2 += pu2[k][t]; }
    pre[FF + blockIdx.x * 32 + t] = r1;
    pre[2 * FF + blockIdx.x * 32 + t] = r2;
  }
}

// ---------------- fused attention + aggregation + projection --------------
// R10: R9's barrier-free wave-per-node body, but TN=8 (wave owns 2 nodes,
// grid = 1250 blocks = 4.88 rounds/CU). Kills the 625-block dispatch tail
// (~40% of kernel life at <50% machine fill) and triples resident waves.
__global__ __launch_bounds__(256) void k_fused(
    const float* __restrict__ nodes, const float* __restrict__ neighbors,
    const float* __restrict__ aspects, const float* __restrict__ pre,
    const float* __restrict__ Wp, const float* __restrict__ bias,
    float* __restrict__ out) {
  const int tid = threadIdx.x;
  const int wid = tid >> 6;
  const int lane = tid & 63;
  const int n0 = blockIdx.x * TN;

  __shared__ float ag[TN][FF];   // 8 KB aggregated rows for this block

  const f32x4 u1v = ((const f32x4*)(pre + FF))[lane];
  const f32x4 u2v = ((const f32x4*)(pre + 2 * FF))[lane];
  const f32x4 vtv = ((const f32x4*)(pre))[lane];
  const float c0 = pre[3 * FF];

  // each wave owns 2 consecutive nodes; no cross-wave interaction until proj
  #pragma unroll 1
  for (int j = 0; j < 2; ++j) {
    const int i = wid * 2 + j;             // slot in ag
    const int n = n0 + i;
    const f32x4* __restrict__ nbg = (const f32x4*)(neighbors + (size_t)n * DD * FF);
    const f32x4* __restrict__ asg = (const f32x4*)(aspects + (size_t)n * DD * FF);

    // ---- phase A: neighbor rows (kept in regs for the agg step) ----
    f32x4 nbv[DD];
    #pragma unroll
    for (int r = 0; r < DD; ++r)
      nbv[r] = __builtin_nontemporal_load(&nbg[r * 64 + lane]);

    float p[DD + 1];
    #pragma unroll
    for (int r = 0; r < DD; ++r) p[r] = DOT4(nbv[r], u1v);

    // ---- phase B: aspect rows (consumed immediately) ----
    #pragma unroll
    for (int r = 0; r < DD; ++r) {
      const f32x4 av = __builtin_nontemporal_load(&asg[r * 64 + lane]);
      p[r] += DOT4(av, u2v);
    }
    const f32x4 nv = ((const f32x4*)(nodes + (size_t)n * FF))[lane];
    p[DD] = DOT4(nv, vtv);

    // 17-value interleaved butterfly; every lane ends with all full sums
    #pragma unroll
    for (int o = 32; o > 0; o >>= 1) {
      #pragma unroll
      for (int r = 0; r < DD + 1; ++r) p[r] += __shfl_xor(p[r], o);
    }

    float esum = 0.f;
    float e[DD];
    #pragma unroll
    for (int r = 0; r < DD; ++r) {
      float s = p[r] + p[DD] + c0;
      s = s > 0.f ? s : 0.2f * s;          // leaky_relu(0.2)
      e[r] = __expf(s);
      esum += e[r];
    }
    const float inv = 1.f / (esum + 1e-16f);

    // lane-local weighted sum -> ag row
    f32x4 acc = (f32x4)(0.f);
    #pragma unroll
    for (int r = 0; r < DD; ++r) {
      acc[0] += e[r] * nbv[r][0];
      acc[1] += e[r] * nbv[r][1];
      acc[2] += e[r] * nbv[r][2];
      acc[3] += e[r] * nbv[r][3];
    }
    acc[0] *= inv; acc[1] *= inv; acc[2] *= inv; acc[3] *= inv;
    ((f32x4*)&ag[i][0])[lane] = acc;
  }

  __syncthreads();   // the only barrier: ag complete

  // ---- projection: out = elu(ag @ Wp.T + bias), ag LDS-resident ----
  float acc[TN];
  #pragma unroll
  for (int i = 0; i < TN; ++i) acc[i] = 0.f;

  const f32x4* wrow = (const f32x4*)(Wp + (size_t)tid * FF);
  for (int f4 = 0; f4 < FF / 4; ++f4) {
    const f32x4 w = wrow[f4];
    #pragma unroll
    for (int i = 0; i < TN; ++i) {
      const f32x4 a = ((const f32x4*)&ag[i][0])[f4];  // LDS broadcast
      acc[i] += DOT4(a, w);
    }
  }

  const float b = bias[tid];
  #pragma unroll
  for (int i = 0; i < TN; ++i) {
    float v = acc[i] + b;
    out[(size_t)(n0 + i) * FF + tid] = v > 0.f ? v : expm1f(v);  // elu
  }
}

extern "C" void kernel_launch(void* const* d_in, const int* in_sizes, int n_in,
                              void* d_out, int out_size, void* d_ws, size_t ws_size,
                              hipStream_t stream) {
  const float* nodes     = (const float*)d_in[0];
  const float* neighbors = (const float*)d_in[1];
  const float* aspects   = (const float*)d_in[2];
  const float* Wp        = (const float*)d_in[3];
  const float* Wa        = (const float*)d_in[4];
  const float* ba        = (const float*)d_in[5];
  const float* a_src     = (const float*)d_in[6];
  const float* a_tgt     = (const float*)d_in[7];
  const float* bias      = (const float*)d_in[8];
  float* out = (float*)d_out;
  float* pre = (float*)d_ws;

  // stage-1 partials parked in the tail of d_out (consumed before k_fused writes)
  float* part = out + (size_t)NN * FF - 16 * 3 * FF;

  k_pre1<<<16, 256, 0, stream>>>(Wp, Wa, a_src, a_tgt, part);
  k_pre2<<<8, 256, 0, stream>>>(Wp, ba, a_src, part, pre);
  k_fused<<<NN / TN, 256, 0, stream>>>(nodes, neighbors, aspects, pre, Wp, bias, out);
}

// Round 11
// 107.551 us; speedup vs baseline: 1.0503x; 1.0014x over previous
//
#include <hip/hip_runtime.h>
#include <hip/hip_bf16.h>
#include <math.h>

#define NN 10000
#define DD 16
#define FF 256
#define TN 8    // nodes per block (4 waves x 2 nodes) -> 1250 blocks

typedef float f32x4 __attribute__((ext_vector_type(4)));
#define DOT4(a, b) ((a)[0]*(b)[0] + (a)[1]*(b)[1] + (a)[2]*(b)[2] + (a)[3]*(b)[3])

// ws layout (floats): [0:256) v_tgt, [256:512) u1, [512:768) u2, [768] c0
// stage-1 partials live in the tail of d_out (read by k_pre2 BEFORE k_fused
// overwrites all of d_out): part[16][3][256] floats.

// ---------------- precomp stage 1: 16 blocks, 16 f's each ----------------
__global__ __launch_bounds__(256) void k_pre1(
    const float* __restrict__ Wp, const float* __restrict__ Wa,
    const float* __restrict__ a_src, const float* __restrict__ a_tgt,
    float* __restrict__ part) {
  const int t = threadIdx.x, b = blockIdx.x;
  float s1 = 0.f, s2 = 0.f, vt = 0.f;
  #pragma unroll
  for (int k = 0; k < 16; ++k) {
    const int f = b * 16 + k;
    const float as = a_src[f];
    s1 += as * Wa[f * 2 * FF + t];        // partial w1[t]
    s2 += as * Wa[f * 2 * FF + FF + t];   // partial w2[t]
    vt += a_tgt[f] * Wp[f * FF + t];      // partial v_tgt[t]
  }
  part[(b * 3 + 0) * FF + t] = s1;
  part[(b * 3 + 1) * FF + t] = s2;
  part[(b * 3 + 2) * FF + t] = vt;
}

// ---------------- precomp stage 2: 8 blocks, 32 output cols each ----------
__global__ __launch_bounds__(256) void k_pre2(
    const float* __restrict__ Wp, const float* __restrict__ ba,
    const float* __restrict__ a_src, const float* __restrict__ part,
    float* __restrict__ pre) {
  __shared__ float w1[FF], w2[FF];
  __shared__ float pu1[8][32], pu2[8][32];
  const int t = threadIdx.x;

  float a0 = 0.f, a1 = 0.f, a2 = 0.f;
  #pragma unroll
  for (int b = 0; b < 16; ++b) {
    a0 += part[(b * 3 + 0) * FF + t];
    a1 += part[(b * 3 + 1) * FF + t];
    a2 += part[(b * 3 + 2) * FF + t];
  }
  w1[t] = a0; w2[t] = a1;
  if (blockIdx.x == 0) {
    pre[t] = a2;                           // v_tgt
    if (t < 64) {
      float cp = 0.f;
      #pragma unroll
      for (int k = 0; k < 4; ++k) cp += ba[t + 64 * k] * a_src[t + 64 * k];
      #pragma unroll
      for (int o = 32; o > 0; o >>= 1) cp += __shfl_xor(cp, o);
      if (t == 0) pre[3 * FF] = cp;        // c0
    }
  }
  __syncthreads();

  const int tc = t & 31;                   // column within slice
  const int gc = t >> 5;                   // g-chunk 0..7
  const int tt = blockIdx.x * 32 + tc;     // global output column
  float u1 = 0.f, u2 = 0.f;
  #pragma unroll 4
  for (int g = gc * 32; g < gc * 32 + 32; ++g) {
    const float wpg = Wp[g * FF + tt];
    u1 += w1[g] * wpg;
    u2 += w2[g] * wpg;
  }
  pu1[gc][tc] = u1; pu2[gc][tc] = u2;
  __syncthreads();
  if (t < 32) {
    float r1 = 0.f, r2 = 0.f;
    #pragma unroll
    for (int k = 0; k < 8; ++k) { r1 += pu1[k][t]; r2 += pu2[k][t]; }
    pre[FF + blockIdx.x * 32 + t] = r1;
    pre[2 * FF + blockIdx.x * 32 + t] = r2;
  }
}

// ---------------- fused attention + aggregation + projection --------------
// R11 single-variable change vs R10: bijective XCD-aware block swizzle
// (T1, m204 formula; nwg=1250 = 8*156+2). Consecutive hardware blocks
// round-robin across XCDs; after remap each XCD streams a private
// contiguous ~42MB slice of neighbors/aspects (read-locality test).
__global__ __launch_bounds__(256) void k_fused(
    const float* __restrict__ nodes, const float* __restrict__ neighbors,
    const float* __restrict__ aspects, const float* __restrict__ pre,
    const float* __restrict__ Wp, const float* __restrict__ bias,
    float* __restrict__ out) {
  const int tid = threadIdx.x;
  const int wid = tid >> 6;
  const int lane = tid & 63;

  // ---- bijective XCD swizzle: nwg=1250, q=156, r=2 ----
  const int orig = blockIdx.x;
  const int xcd = orig & 7;          // hardware XCD of this block (round-robin)
  const int idx = orig >> 3;         // position within this XCD's sequence
  const int q = 1250 >> 3, r = 1250 & 7;  // 156, 2
  const int base = (xcd < r) ? xcd * (q + 1) : r * (q + 1) + (xcd - r) * q;
  const int wg = base + idx;         // contiguous node-chunk per XCD
  const int n0 = wg * TN;

  __shared__ float ag[TN][FF];   // 8 KB aggregated rows for this block

  const f32x4 u1v = ((const f32x4*)(pre + FF))[lane];
  const f32x4 u2v = ((const f32x4*)(pre + 2 * FF))[lane];
  const f32x4 vtv = ((const f32x4*)(pre))[lane];
  const float c0 = pre[3 * FF];

  // each wave owns 2 consecutive nodes; no cross-wave interaction until proj
  #pragma unroll 1
  for (int j = 0; j < 2; ++j) {
    const int i = wid * 2 + j;             // slot in ag
    const int n = n0 + i;
    const f32x4* __restrict__ nbg = (const f32x4*)(neighbors + (size_t)n * DD * FF);
    const f32x4* __restrict__ asg = (const f32x4*)(aspects + (size_t)n * DD * FF);

    // ---- phase A: neighbor rows (kept in regs for the agg step) ----
    f32x4 nbv[DD];
    #pragma unroll
    for (int r2_ = 0; r2_ < DD; ++r2_)
      nbv[r2_] = __builtin_nontemporal_load(&nbg[r2_ * 64 + lane]);

    float p[DD + 1];
    #pragma unroll
    for (int r2_ = 0; r2_ < DD; ++r2_) p[r2_] = DOT4(nbv[r2_], u1v);

    // ---- phase B: aspect rows (consumed immediately) ----
    #pragma unroll
    for (int r2_ = 0; r2_ < DD; ++r2_) {
      const f32x4 av = __builtin_nontemporal_load(&asg[r2_ * 64 + lane]);
      p[r2_] += DOT4(av, u2v);
    }
    const f32x4 nv = ((const f32x4*)(nodes + (size_t)n * FF))[lane];
    p[DD] = DOT4(nv, vtv);

    // 17-value interleaved butterfly; every lane ends with all full sums
    #pragma unroll
    for (int o = 32; o > 0; o >>= 1) {
      #pragma unroll
      for (int r2_ = 0; r2_ < DD + 1; ++r2_) p[r2_] += __shfl_xor(p[r2_], o);
    }

    float esum = 0.f;
    float e[DD];
    #pragma unroll
    for (int r2_ = 0; r2_ < DD; ++r2_) {
      float s = p[r2_] + p[DD] + c0;
      s = s > 0.f ? s : 0.2f * s;          // leaky_relu(0.2)
      e[r2_] = __expf(s);
      esum += e[r2_];
    }
    const float inv = 1.f / (esum + 1e-16f);

    // lane-local weighted sum -> ag row
    f32x4 acc = (f32x4)(0.f);
    #pragma unroll
    for (int r2_ = 0; r2_ < DD; ++r2_) {
      acc[0] += e[r2_] * nbv[r2_][0];
      acc[1] += e[r2_] * nbv[r2_][1];
      acc[2] += e[r2_] * nbv[r2_][2];
      acc[3] += e[r2_] * nbv[r2_][3];
    }
    acc[0] *= inv; acc[1] *= inv; acc[2] *= inv; acc[3] *= inv;
    ((f32x4*)&ag[i][0])[lane] = acc;
  }

  __syncthreads();   // the only barrier: ag complete

  // ---- projection: out = elu(ag @ Wp.T + bias), ag LDS-resident ----
  float acc[TN];
  #pragma unroll
  for (int i = 0; i < TN; ++i) acc[i] = 0.f;

  const f32x4* wrow = (const f32x4*)(Wp + (size_t)tid * FF);
  for (int f4 = 0; f4 < FF / 4; ++f4) {
    const f32x4 w = wrow[f4];
    #pragma unroll
    for (int i = 0; i < TN; ++i) {
      const f32x4 a = ((const f32x4*)&ag[i][0])[f4];  // LDS broadcast
      acc[i] += DOT4(a, w);
    }
  }

  const float b = bias[tid];
  #pragma unroll
  for (int i = 0; i < TN; ++i) {
    float v = acc[i] + b;
    out[(size_t)(n0 + i) * FF + tid] = v > 0.f ? v : expm1f(v);  // elu
  }
}

extern "C" void kernel_launch(void* const* d_in, const int* in_sizes, int n_in,
                              void* d_out, int out_size, void* d_ws, size_t ws_size,
                              hipStream_t stream) {
  const float* nodes     = (const float*)d_in[0];
  const float* neighbors = (const float*)d_in[1];
  const float* aspects   = (const float*)d_in[2];
  const float* Wp        = (const float*)d_in[3];
  const float* Wa        = (const float*)d_in[4];
  const float* ba        = (const float*)d_in[5];
  const float* a_src     = (const float*)d_in[6];
  const float* a_tgt     = (const float*)d_in[7];
  const float* bias      = (const float*)d_in[8];
  float* out = (float*)d_out;
  float* pre = (float*)d_ws;

  // stage-1 partials parked in the tail of d_out (consumed before k_fused writes)
  float* part = out + (size_t)NN * FF - 16 * 3 * FF;

  k_pre1<<<16, 256, 0, stream>>>(Wp, Wa, a_src, a_tgt, part);
  k_pre2<<<8, 256, 0, stream>>>(Wp, ba, a_src, part, pre);
  k_fused<<<NN / TN, 256, 0, stream>>>(nodes, neighbors, aspects, pre, Wp, bias, out);
}